// Round 1
// baseline (2611.264 us; speedup 1.0000x reference)
//
#include <hip/hip_runtime.h>
#include <math.h>

#define B_ 2
#define T_ 2048
#define D_ 1024
#define H_ 16
#define HD_ 64
#define M_ 16384
#define SCALE_F 4096.0f
#define LDP 3072

using short8 = __attribute__((ext_vector_type(8))) short;
using bf16x8 = __attribute__((ext_vector_type(8))) __bf16;
using f32x4  = __attribute__((ext_vector_type(4))) float;

__device__ __forceinline__ unsigned short f2bf(float x){
  unsigned u = __builtin_bit_cast(unsigned, x);
  u += 0x7fffu + ((u >> 16) & 1u);          // RNE
  return (unsigned short)(u >> 16);
}
__device__ __forceinline__ float bf2f(unsigned short h){
  unsigned u = ((unsigned)h) << 16;
  return __builtin_bit_cast(float, u);
}
__device__ __forceinline__ float bfround(float x){ return bf2f(f2bf(x)); }

__device__ __forceinline__ float wsum(float v){
  #pragma unroll
  for (int off = 32; off; off >>= 1) v += __shfl_xor(v, off);
  return v;
}
__device__ __forceinline__ float wmax(float v){
  #pragma unroll
  for (int off = 32; off; off >>= 1) v = fmaxf(v, __shfl_xor(v, off));
  return v;
}

// C[m, n0+ n] = sum_k A[m,k] * W[n,k] + bias[n]   (A: M x 1024 fp32, W row-major N x 1024)
// COMP=true: bf16x3 error-compensated (hi/lo split on both operands).
// Block tile 128(M) x 64(N), BK=32, 256 threads (4 waves, each 32x64).
template<bool COMP>
__global__ __launch_bounds__(256)
void gemm_bt(const float* __restrict__ A, int lda,
             const float* __restrict__ W0, const float* __restrict__ W1, const float* __restrict__ W2,
             const float* __restrict__ bias0, const float* __restrict__ bias1, const float* __restrict__ bias2,
             float* __restrict__ C, int ldc)
{
  __shared__ short Ahi[128*40];
  __shared__ short Bhi[64*40];
  __shared__ short Alo[COMP ? 128*40 : 8];
  __shared__ short Blo[COMP ? 64*40 : 8];

  const int tid = threadIdx.x;
  const int n0 = blockIdx.x * 64;
  const int m0 = blockIdx.y * 128;
  const int seg = n0 >> 10;
  const float* W    = (seg == 0) ? W0 : (seg == 1) ? W1 : W2;
  const float* bias = (seg == 0) ? bias0 : (seg == 1) ? bias1 : bias2;
  const int nw = n0 & 1023;
  const int lane = tid & 63, wv = tid >> 6;
  const int mi = lane & 15, quad = lane >> 4;

  f32x4 acc[2][4];
  #pragma unroll
  for (int a = 0; a < 2; ++a)
    #pragma unroll
    for (int b = 0; b < 4; ++b)
      acc[a][b] = (f32x4){0.f, 0.f, 0.f, 0.f};

  for (int k0 = 0; k0 < 1024; k0 += 32){
    __syncthreads();
    // stage A tile: 128 rows x 32 k (fp32 -> bf16 hi/lo)
    #pragma unroll
    for (int i = 0; i < 4; ++i){
      int f = tid + i*256;
      int r = f >> 3, c4 = f & 7;
      float4 v = *(const float4*)(A + (size_t)(m0 + r)*lda + k0 + c4*4);
      unsigned short h0=f2bf(v.x), h1=f2bf(v.y), h2=f2bf(v.z), h3=f2bf(v.w);
      uint2 hh; hh.x = (unsigned)h0 | ((unsigned)h1 << 16);
                hh.y = (unsigned)h2 | ((unsigned)h3 << 16);
      *(uint2*)(Ahi + r*40 + c4*4) = hh;
      if constexpr (COMP){
        unsigned short l0=f2bf(v.x-bf2f(h0)), l1=f2bf(v.y-bf2f(h1));
        unsigned short l2=f2bf(v.z-bf2f(h2)), l3=f2bf(v.w-bf2f(h3));
        uint2 ll; ll.x = (unsigned)l0 | ((unsigned)l1 << 16);
                  ll.y = (unsigned)l2 | ((unsigned)l3 << 16);
        *(uint2*)(Alo + r*40 + c4*4) = ll;
      }
    }
    // stage B tile: 64 rows of W x 32 k
    #pragma unroll
    for (int i = 0; i < 2; ++i){
      int f = tid + i*256;
      int r = f >> 3, c4 = f & 7;
      float4 v = *(const float4*)(W + (size_t)(nw + r)*1024 + k0 + c4*4);
      unsigned short h0=f2bf(v.x), h1=f2bf(v.y), h2=f2bf(v.z), h3=f2bf(v.w);
      uint2 hh; hh.x = (unsigned)h0 | ((unsigned)h1 << 16);
                hh.y = (unsigned)h2 | ((unsigned)h3 << 16);
      *(uint2*)(Bhi + r*40 + c4*4) = hh;
      if constexpr (COMP){
        unsigned short l0=f2bf(v.x-bf2f(h0)), l1=f2bf(v.y-bf2f(h1));
        unsigned short l2=f2bf(v.z-bf2f(h2)), l3=f2bf(v.w-bf2f(h3));
        uint2 ll; ll.x = (unsigned)l0 | ((unsigned)l1 << 16);
                  ll.y = (unsigned)l2 | ((unsigned)l3 << 16);
        *(uint2*)(Blo + r*40 + c4*4) = ll;
      }
    }
    __syncthreads();

    bf16x8 ah[2], al[2], bh[4], bl[4];
    #pragma unroll
    for (int a = 0; a < 2; ++a){
      int row = wv*32 + a*16 + mi;
      ah[a] = __builtin_bit_cast(bf16x8, *(const short8*)(Ahi + row*40 + quad*8));
      if constexpr (COMP)
        al[a] = __builtin_bit_cast(bf16x8, *(const short8*)(Alo + row*40 + quad*8));
    }
    #pragma unroll
    for (int b = 0; b < 4; ++b){
      int row = b*16 + mi;
      bh[b] = __builtin_bit_cast(bf16x8, *(const short8*)(Bhi + row*40 + quad*8));
      if constexpr (COMP)
        bl[b] = __builtin_bit_cast(bf16x8, *(const short8*)(Blo + row*40 + quad*8));
    }
    #pragma unroll
    for (int a = 0; a < 2; ++a)
      #pragma unroll
      for (int b = 0; b < 4; ++b){
        if constexpr (COMP){
          acc[a][b] = __builtin_amdgcn_mfma_f32_16x16x32_bf16(al[a], bh[b], acc[a][b], 0, 0, 0);
          acc[a][b] = __builtin_amdgcn_mfma_f32_16x16x32_bf16(ah[a], bl[b], acc[a][b], 0, 0, 0);
        }
        acc[a][b] = __builtin_amdgcn_mfma_f32_16x16x32_bf16(ah[a], bh[b], acc[a][b], 0, 0, 0);
      }
  }
  // epilogue: C/D layout col=lane&15, row=quad*4+reg (m89/m91-verified)
  #pragma unroll
  for (int a = 0; a < 2; ++a)
    #pragma unroll
    for (int b = 0; b < 4; ++b)
      #pragma unroll
      for (int r = 0; r < 4; ++r){
        int row  = m0 + wv*32 + a*16 + quad*4 + r;
        int colл = 0; (void)colл;
        int coll = b*16 + mi;
        C[(size_t)row*ldc + n0 + coll] = acc[a][b][r] + bias[nw + coll];
      }
}

// L2-normalize q (cols 0..1023) and k (cols 1024..2047) of P, per token row.
__global__ __launch_bounds__(256)
void norm_qk(float* __restrict__ P)
{
  const int row = blockIdx.x, tid = threadIdx.x;
  const int lane = tid & 63, wv = tid >> 6;
  const size_t base = (size_t)row * LDP;
  float4 q4 = *(float4*)(P + base + tid*4);
  float4 k4 = *(float4*)(P + base + 1024 + tid*4);
  float sq = q4.x*q4.x + q4.y*q4.y + q4.z*q4.z + q4.w*q4.w;
  float sk = k4.x*k4.x + k4.y*k4.y + k4.z*k4.z + k4.w*k4.w;
  sq = wsum(sq); sk = wsum(sk);
  __shared__ float rq[4], rk[4];
  if (lane == 0){ rq[wv] = sq; rk[wv] = sk; }
  __syncthreads();
  float tq = rq[0]+rq[1]+rq[2]+rq[3];
  float tk = rk[0]+rk[1]+rk[2]+rk[3];
  float cq = 1.f / fmaxf(sqrtf(tq), 1e-12f);
  float ck = 1.f / fmaxf(sqrtf(tk), 1e-12f);
  q4.x*=cq; q4.y*=cq; q4.z*=cq; q4.w*=cq;
  k4.x*=ck; k4.y*=ck; k4.z*=ck; k4.w*=ck;
  *(float4*)(P + base + tid*4) = q4;
  *(float4*)(P + base + 1024 + tid*4) = k4;
}

// Fused causal flash attention + KNN memory attention + gate + bf16 round.
// Block: 256 threads = 4 waves; each wave handles 4 consecutive query rows; lane = head dim.
__global__ __launch_bounds__(256)
void attn_knn(const float* __restrict__ P,
              const float* __restrict__ mem_bank,
              const int* __restrict__ knn_idx,
              const float* __restrict__ gate_bias,
              float* __restrict__ comb)
{
  __shared__ float Ks[64][68];
  __shared__ float Vs[64][68];
  __shared__ float qs[16][68];
  __shared__ float ps[4][4][64];

  const int b = blockIdx.z, h = blockIdx.y;
  const int r0 = blockIdx.x * 16;
  const int tid = threadIdx.x, lane = tid & 63, wv = tid >> 6;
  const size_t baseP = (size_t)b * T_ * LDP;

  { int row = tid >> 4, c4 = tid & 15;
    *(float4*)&qs[row][c4*4] =
      *(const float4*)(P + baseP + (size_t)(r0 + row)*LDP + h*HD_ + c4*4); }

  float o[4]  = {0.f, 0.f, 0.f, 0.f};
  float mr[4] = {-INFINITY, -INFINITY, -INFINITY, -INFINITY};
  float lr[4] = {0.f, 0.f, 0.f, 0.f};

  const int ntiles = (r0 + 15)/64 + 1;
  for (int jt = 0; jt < ntiles; ++jt){
    __syncthreads();
    #pragma unroll
    for (int i = 0; i < 4; ++i){
      int f = tid + i*256;
      int row = f >> 4, c4 = f & 15;
      size_t g = baseP + (size_t)(jt*64 + row)*LDP + h*HD_ + c4*4;
      *(float4*)&Ks[row][c4*4] = *(const float4*)(P + g + 1024);
      *(float4*)&Vs[row][c4*4] = *(const float4*)(P + g + 2048);
    }
    __syncthreads();

    // QK: lane = key within tile; 4 rows share the K read
    float dt[4] = {0.f, 0.f, 0.f, 0.f};
    #pragma unroll
    for (int dd = 0; dd < 16; ++dd){
      float4 k4 = *(const float4*)&Ks[lane][dd*4];
      #pragma unroll
      for (int rr = 0; rr < 4; ++rr){
        float4 q4 = *(const float4*)&qs[wv*4+rr][dd*4];
        dt[rr] += q4.x*k4.x + q4.y*k4.y + q4.z*k4.z + q4.w*k4.w;
      }
    }
    float alv[4] = {1.f,1.f,1.f,1.f};
    bool act[4];
    #pragma unroll
    for (int rr = 0; rr < 4; ++rr){
      int trow = r0 + wv*4 + rr;
      act[rr] = (jt*64 <= trow);
      if (!act[rr]) continue;                    // wave-uniform
      float logit = (jt*64 + lane <= trow) ? dt[rr]*SCALE_F : -INFINITY;
      float tm = wmax(logit);
      float mnew = fmaxf(mr[rr], tm);
      float p = __expf(logit - mnew);
      float tsum = wsum(p);
      float alpha = __expf(mr[rr] - mnew);
      lr[rr] = lr[rr]*alpha + tsum;
      mr[rr] = mnew;
      alv[rr] = alpha;
      ps[wv][rr][lane] = p;                      // same-wave LDS, in-order
    }
    // PV: lane = head dim
    #pragma unroll
    for (int rr = 0; rr < 4; ++rr){
      if (!act[rr]) continue;
      float a2 = 0.f;
      #pragma unroll
      for (int j4 = 0; j4 < 16; ++j4){
        float4 p4 = *(const float4*)&ps[wv][rr][j4*4];
        a2 += p4.x*Vs[j4*4+0][lane] + p4.y*Vs[j4*4+1][lane]
            + p4.z*Vs[j4*4+2][lane] + p4.w*Vs[j4*4+3][lane];
      }
      o[rr] = o[rr]*alv[rr] + a2;
    }
  }

  const float g = gate_bias[h];
  #pragma unroll
  for (int rr = 0; rr < 4; ++rr){
    int trow = r0 + wv*4 + rr;
    float qkv = o[rr] / lr[rr];
    float qd = qs[wv*4+rr][lane];
    const int* kidx = knn_idx + ((size_t)b*T_ + trow)*3;
    int idxs[3]; float dts[3]; float mx = -INFINITY;
    #pragma unroll
    for (int kk = 0; kk < 3; ++kk){
      int idx = kidx[kk];
      idxs[kk] = idx;
      const float* mk = mem_bank + (((size_t)b*M_ + idx)*2 + 0)*D_ + h*HD_;
      float dkk = wsum(qd * mk[lane]) * SCALE_F;
      dts[kk] = dkk;
      mx = fmaxf(mx, dkk);
    }
    float e0 = __expf(dts[0]-mx), e1 = __expf(dts[1]-mx), e2 = __expf(dts[2]-mx);
    float inv = 1.f/(e0+e1+e2);
    const float* mv0 = mem_bank + (((size_t)b*M_ + idxs[0])*2 + 1)*D_ + h*HD_;
    const float* mv1 = mem_bank + (((size_t)b*M_ + idxs[1])*2 + 1)*D_ + h*HD_;
    const float* mv2 = mem_bank + (((size_t)b*M_ + idxs[2])*2 + 1)*D_ + h*HD_;
    float ov = e0*inv*mv0[lane] + e1*inv*mv1[lane] + e2*inv*mv2[lane];
    float c = ov*g + qkv*(1.f - g);
    comb[((size_t)b*T_ + trow)*D_ + h*HD_ + lane] = bfround(c);   // ref's bf16 cast
  }
}

extern "C" void kernel_launch(void* const* d_in, const int* in_sizes, int n_in,
                              void* d_out, int out_size, void* d_ws, size_t ws_size,
                              hipStream_t stream)
{
  (void)in_sizes; (void)n_in; (void)out_size; (void)ws_size;
  const float* x    = (const float*)d_in[0];
  const float* Wq   = (const float*)d_in[1];
  const float* bq   = (const float*)d_in[2];
  const float* Wk   = (const float*)d_in[3];
  const float* bk   = (const float*)d_in[4];
  const float* Wv   = (const float*)d_in[5];
  const float* bv   = (const float*)d_in[6];
  const float* Wo   = (const float*)d_in[7];
  const float* bo   = (const float*)d_in[8];
  const float* gate = (const float*)d_in[9];
  const float* mem  = (const float*)d_in[10];
  const int*   knn  = (const int*)d_in[11];

  float* P    = (float*)d_ws;                       // (B*T, 3072) = q|k|v
  float* comb = P + (size_t)4096 * LDP;             // (B*T, 1024) bf16-rounded fp32

  // fused QKV projection: C(4096x3072) = x(4096x1024) . [Wq;Wk;Wv]^T + bias
  gemm_bt<true><<<dim3(48, 32), 256, 0, stream>>>(x, D_, Wq, Wk, Wv, bq, bk, bv, P, LDP);
  norm_qk<<<4096, 256, 0, stream>>>(P);
  attn_knn<<<dim3(T_/16, H_, B_), 256, 0, stream>>>(P, mem, knn, gate, comb);
  // output projection: d_out(4096x1024) = comb . Wo^T + bo  (plain bf16: comb is bf16-exact)
  gemm_bt<false><<<dim3(16, 32), 256, 0, stream>>>(comb, D_, Wo, Wo, Wo, bo, bo, bo,
                                                   (float*)d_out, D_);
}

// Round 2
// 781.185 us; speedup vs baseline: 3.3427x; 3.3427x over previous
//
#include <hip/hip_runtime.h>
#include <math.h>

#define B_ 2
#define T_ 2048
#define D_ 1024
#define H_ 16
#define HD_ 64
#define M_ 16384
#define SCALE_F 4096.0f
#define LDP 3072
#define ST 72            // LDS row stride in shorts (64 + 8 pad; keeps b128 16B-aligned, bank-even)

using short8 = __attribute__((ext_vector_type(8))) short;
using bf16x8 = __attribute__((ext_vector_type(8))) __bf16;
using f32x4  = __attribute__((ext_vector_type(4))) float;

__device__ __forceinline__ unsigned short f2bf(float x){
  unsigned u = __builtin_bit_cast(unsigned, x);
  u += 0x7fffu + ((u >> 16) & 1u);          // RNE
  return (unsigned short)(u >> 16);
}
__device__ __forceinline__ float bf2f(unsigned short h){
  unsigned u = ((unsigned)h) << 16;
  return __builtin_bit_cast(float, u);
}
__device__ __forceinline__ float bfround(float x){ return bf2f(f2bf(x)); }

__device__ __forceinline__ float wsum(float v){
  #pragma unroll
  for (int off = 32; off; off >>= 1) v += __shfl_xor(v, off);
  return v;
}

// ---------------------------------------------------------------------------
// GEMM: C[m, n0+n] = sum_k A[m,k]*W[n,k] + bias[n].  COMP: bf16x3 compensated
// (only for segments 0,1 = q,k; v and the output proj don't need it).
// Tile 128x64, BK=32, 256 threads / 4 waves.
// ---------------------------------------------------------------------------
template<bool COMP>
__global__ __launch_bounds__(256)
void gemm_bt(const float* __restrict__ A, int lda,
             const float* __restrict__ W0, const float* __restrict__ W1, const float* __restrict__ W2,
             const float* __restrict__ bias0, const float* __restrict__ bias1, const float* __restrict__ bias2,
             float* __restrict__ C, int ldc)
{
  __shared__ short Ahi[128*40];
  __shared__ short Bhi[64*40];
  __shared__ short Alo[COMP ? 128*40 : 8];
  __shared__ short Blo[COMP ? 64*40 : 8];

  const int tid = threadIdx.x;
  const int n0 = blockIdx.x * 64;
  const int m0 = blockIdx.y * 128;
  const int seg = n0 >> 10;
  const float* W    = (seg == 0) ? W0 : (seg == 1) ? W1 : W2;
  const float* bias = (seg == 0) ? bias0 : (seg == 1) ? bias1 : bias2;
  const bool comp = COMP && (seg < 2);
  const int nw = n0 & 1023;
  const int lane = tid & 63, wv = tid >> 6;
  const int mi = lane & 15, quad = lane >> 4;

  f32x4 acc[2][4];
  #pragma unroll
  for (int a = 0; a < 2; ++a)
    #pragma unroll
    for (int b = 0; b < 4; ++b)
      acc[a][b] = (f32x4){0.f, 0.f, 0.f, 0.f};

  for (int k0 = 0; k0 < 1024; k0 += 32){
    __syncthreads();
    #pragma unroll
    for (int i = 0; i < 4; ++i){
      int f = tid + i*256;
      int r = f >> 3, c4 = f & 7;
      float4 v = *(const float4*)(A + (size_t)(m0 + r)*lda + k0 + c4*4);
      unsigned short h0=f2bf(v.x), h1=f2bf(v.y), h2=f2bf(v.z), h3=f2bf(v.w);
      uint2 hh; hh.x = (unsigned)h0 | ((unsigned)h1 << 16);
                hh.y = (unsigned)h2 | ((unsigned)h3 << 16);
      *(uint2*)(Ahi + r*40 + c4*4) = hh;
      if constexpr (COMP){
        if (comp){
          unsigned short l0=f2bf(v.x-bf2f(h0)), l1=f2bf(v.y-bf2f(h1));
          unsigned short l2=f2bf(v.z-bf2f(h2)), l3=f2bf(v.w-bf2f(h3));
          uint2 ll; ll.x = (unsigned)l0 | ((unsigned)l1 << 16);
                    ll.y = (unsigned)l2 | ((unsigned)l3 << 16);
          *(uint2*)(Alo + r*40 + c4*4) = ll;
        }
      }
    }
    #pragma unroll
    for (int i = 0; i < 2; ++i){
      int f = tid + i*256;
      int r = f >> 3, c4 = f & 7;
      float4 v = *(const float4*)(W + (size_t)(nw + r)*1024 + k0 + c4*4);
      unsigned short h0=f2bf(v.x), h1=f2bf(v.y), h2=f2bf(v.z), h3=f2bf(v.w);
      uint2 hh; hh.x = (unsigned)h0 | ((unsigned)h1 << 16);
                hh.y = (unsigned)h2 | ((unsigned)h3 << 16);
      *(uint2*)(Bhi + r*40 + c4*4) = hh;
      if constexpr (COMP){
        if (comp){
          unsigned short l0=f2bf(v.x-bf2f(h0)), l1=f2bf(v.y-bf2f(h1));
          unsigned short l2=f2bf(v.z-bf2f(h2)), l3=f2bf(v.w-bf2f(h3));
          uint2 ll; ll.x = (unsigned)l0 | ((unsigned)l1 << 16);
                    ll.y = (unsigned)l2 | ((unsigned)l3 << 16);
          *(uint2*)(Blo + r*40 + c4*4) = ll;
        }
      }
    }
    __syncthreads();

    bf16x8 ah[2], al[2], bh[4], bl[4];
    #pragma unroll
    for (int a = 0; a < 2; ++a){
      int row = wv*32 + a*16 + mi;
      ah[a] = __builtin_bit_cast(bf16x8, *(const short8*)(Ahi + row*40 + quad*8));
      if constexpr (COMP)
        if (comp) al[a] = __builtin_bit_cast(bf16x8, *(const short8*)(Alo + row*40 + quad*8));
    }
    #pragma unroll
    for (int b = 0; b < 4; ++b){
      int row = b*16 + mi;
      bh[b] = __builtin_bit_cast(bf16x8, *(const short8*)(Bhi + row*40 + quad*8));
      if constexpr (COMP)
        if (comp) bl[b] = __builtin_bit_cast(bf16x8, *(const short8*)(Blo + row*40 + quad*8));
    }
    #pragma unroll
    for (int a = 0; a < 2; ++a)
      #pragma unroll
      for (int b = 0; b < 4; ++b){
        if constexpr (COMP){
          if (comp){
            acc[a][b] = __builtin_amdgcn_mfma_f32_16x16x32_bf16(al[a], bh[b], acc[a][b], 0, 0, 0);
            acc[a][b] = __builtin_amdgcn_mfma_f32_16x16x32_bf16(ah[a], bl[b], acc[a][b], 0, 0, 0);
          }
        }
        acc[a][b] = __builtin_amdgcn_mfma_f32_16x16x32_bf16(ah[a], bh[b], acc[a][b], 0, 0, 0);
      }
  }
  #pragma unroll
  for (int a = 0; a < 2; ++a)
    #pragma unroll
    for (int b = 0; b < 4; ++b)
      #pragma unroll
      for (int r = 0; r < 4; ++r){
        int row  = m0 + wv*32 + a*16 + quad*4 + r;
        int coll = b*16 + mi;
        C[(size_t)row*ldc + n0 + coll] = acc[a][b][r] + bias[nw + coll];
      }
}

// ---------------------------------------------------------------------------
// Normalize q,k rows of P and emit head-major bf16 arrays:
// Qhi/Qlo/Khi/Klo/Vbf [(b*H+h)*T + t]*64 + d
// ---------------------------------------------------------------------------
__global__ __launch_bounds__(256)
void norm_split(const float* __restrict__ P,
                unsigned short* __restrict__ Qhi, unsigned short* __restrict__ Qlo,
                unsigned short* __restrict__ Khi, unsigned short* __restrict__ Klo,
                unsigned short* __restrict__ Vbf)
{
  const int row = blockIdx.x, tid = threadIdx.x;
  const int bb = row >> 11, t = row & 2047;
  const int lane = tid & 63, wv = tid >> 6;
  const size_t base = (size_t)row * LDP;
  float4 q4 = *(const float4*)(P + base + tid*4);
  float4 k4 = *(const float4*)(P + base + 1024 + tid*4);
  float4 v4 = *(const float4*)(P + base + 2048 + tid*4);
  float sq = q4.x*q4.x + q4.y*q4.y + q4.z*q4.z + q4.w*q4.w;
  float sk = k4.x*k4.x + k4.y*k4.y + k4.z*k4.z + k4.w*k4.w;
  sq = wsum(sq); sk = wsum(sk);
  __shared__ float rq[4], rk[4];
  if (lane == 0){ rq[wv] = sq; rk[wv] = sk; }
  __syncthreads();
  float cq = 1.f / fmaxf(sqrtf(rq[0]+rq[1]+rq[2]+rq[3]), 1e-12f);
  float ck = 1.f / fmaxf(sqrtf(rk[0]+rk[1]+rk[2]+rk[3]), 1e-12f);
  float qf[4] = {q4.x*cq, q4.y*cq, q4.z*cq, q4.w*cq};
  float kf[4] = {k4.x*ck, k4.y*ck, k4.z*ck, k4.w*ck};
  float vf[4] = {v4.x, v4.y, v4.z, v4.w};

  const int h = tid >> 4, d0 = (tid & 15)*4;
  const size_t ob = ((size_t)(bb*H_ + h)*T_ + t)*64 + d0;

  uint2 qh, ql, kh, kl, vv;
  unsigned short t0,t1,t2,t3;
  t0=f2bf(qf[0]); t1=f2bf(qf[1]); t2=f2bf(qf[2]); t3=f2bf(qf[3]);
  qh.x = t0 | ((unsigned)t1<<16); qh.y = t2 | ((unsigned)t3<<16);
  ql.x = f2bf(qf[0]-bf2f(t0)) | ((unsigned)f2bf(qf[1]-bf2f(t1))<<16);
  ql.y = f2bf(qf[2]-bf2f(t2)) | ((unsigned)f2bf(qf[3]-bf2f(t3))<<16);
  t0=f2bf(kf[0]); t1=f2bf(kf[1]); t2=f2bf(kf[2]); t3=f2bf(kf[3]);
  kh.x = t0 | ((unsigned)t1<<16); kh.y = t2 | ((unsigned)t3<<16);
  kl.x = f2bf(kf[0]-bf2f(t0)) | ((unsigned)f2bf(kf[1]-bf2f(t1))<<16);
  kl.y = f2bf(kf[2]-bf2f(t2)) | ((unsigned)f2bf(kf[3]-bf2f(t3))<<16);
  vv.x = f2bf(vf[0]) | ((unsigned)f2bf(vf[1])<<16);
  vv.y = f2bf(vf[2]) | ((unsigned)f2bf(vf[3])<<16);
  *(uint2*)(Qhi + ob) = qh;  *(uint2*)(Qlo + ob) = ql;
  *(uint2*)(Khi + ob) = kh;  *(uint2*)(Klo + ob) = kl;
  *(uint2*)(Vbf + ob) = vv;
}

// ---------------------------------------------------------------------------
// MFMA flash attention + KNN + gate.  Grid (T/64, H, B), 256 thr = 4 waves,
// each wave owns 16 q-rows.  S^T = mfma(K, Q) (bf16x3); PV via per-wave LDS
// round-trip for P; V staged transposed (2 keys packed per dword).
// ---------------------------------------------------------------------------
__global__ __launch_bounds__(256)
void attn_knn(const unsigned short* __restrict__ Qhi, const unsigned short* __restrict__ Qlo,
              const unsigned short* __restrict__ Khi_g, const unsigned short* __restrict__ Klo_g,
              const unsigned short* __restrict__ Vbf,
              const float* __restrict__ mem_bank, const int* __restrict__ knn_idx,
              const float* __restrict__ gate_bias, float* __restrict__ comb)
{
  __shared__ char smpool[36864];
  unsigned short* Kh = (unsigned short*)smpool;            // 64*72 shorts
  unsigned short* Kl = (unsigned short*)(smpool + 9216);
  unsigned short* Vt = (unsigned short*)(smpool + 18432);  // [d][key] packed pairs
  unsigned short* Pb = (unsigned short*)(smpool + 27648);  // 4 waves * 16*72
  float* qkvs = (float*)smpool;                            // overlay (64 x 68 fp32)

  const int bb = blockIdx.z, h = blockIdx.y;
  const int r0 = blockIdx.x * 64;
  const int tid = threadIdx.x, lane = tid & 63, wv = tid >> 6;
  const int mi = lane & 15, quad = lane >> 4;
  const size_t hb = (size_t)(bb*H_ + h)*T_;      // head base (rows)

  // Q fragments straight from global (B-operand: n = q row = mi, k = quad*8+j)
  const int qrow = r0 + wv*16 + mi;
  bf16x8 qh[2], ql[2];
  #pragma unroll
  for (int ks = 0; ks < 2; ++ks){
    qh[ks] = __builtin_bit_cast(bf16x8, *(const uint4*)(Qhi + (hb + qrow)*64 + ks*32 + quad*8));
    ql[ks] = __builtin_bit_cast(bf16x8, *(const uint4*)(Qlo + (hb + qrow)*64 + ks*32 + quad*8));
  }

  f32x4 O[4];
  #pragma unroll
  for (int dn = 0; dn < 4; ++dn) O[dn] = (f32x4){0.f,0.f,0.f,0.f};
  float mr = -INFINITY, lr = 0.f;

  const int ntiles = blockIdx.x + 1;
  for (int jt = 0; jt < ntiles; ++jt){
    __syncthreads();
    // stage K hi/lo (b64 chunks: bank-even 2-way)
    #pragma unroll
    for (int i = 0; i < 4; ++i){
      int idx = tid + i*256;
      int row = idx >> 4, c4 = idx & 15;
      size_t g = (hb + jt*64 + row)*64 + c4*4;
      *(uint2*)(Kh + row*ST + c4*4) = *(const uint2*)(Khi_g + g);
      *(uint2*)(Kl + row*ST + c4*4) = *(const uint2*)(Klo_g + g);
    }
    // stage V transposed: pack keys (2r,2r+1) into dwords -> Vt[d][key]
    #pragma unroll
    for (int i = 0; i < 2; ++i){
      int idx = tid + i*256;
      int rp = idx & 31, d4 = idx >> 5;     // d4 in 0..15
      size_t g = (hb + jt*64 + 2*rp)*64 + d4*4;
      ushort4 a = *(const ushort4*)(Vbf + g);
      ushort4 b = *(const ushort4*)(Vbf + g + 64);
      unsigned* vt = (unsigned*)Vt;
      vt[(d4*4+0)*36 + rp] = (unsigned)a.x | ((unsigned)b.x << 16);
      vt[(d4*4+1)*36 + rp] = (unsigned)a.y | ((unsigned)b.y << 16);
      vt[(d4*4+2)*36 + rp] = (unsigned)a.z | ((unsigned)b.z << 16);
      vt[(d4*4+3)*36 + rp] = (unsigned)a.w | ((unsigned)b.w << 16);
    }
    __syncthreads();

    // QK: S^T[key][q], 4 key-tiles, compensated bf16x3
    f32x4 st[4];
    #pragma unroll
    for (int mt = 0; mt < 4; ++mt) st[mt] = (f32x4){0.f,0.f,0.f,0.f};
    #pragma unroll
    for (int mt = 0; mt < 4; ++mt){
      int krow = mt*16 + mi;
      #pragma unroll
      for (int ks = 0; ks < 2; ++ks){
        bf16x8 kh = __builtin_bit_cast(bf16x8, *(const short8*)(Kh + krow*ST + ks*32 + quad*8));
        bf16x8 kl = __builtin_bit_cast(bf16x8, *(const short8*)(Kl + krow*ST + ks*32 + quad*8));
        st[mt] = __builtin_amdgcn_mfma_f32_16x16x32_bf16(kl, qh[ks], st[mt], 0, 0, 0);
        st[mt] = __builtin_amdgcn_mfma_f32_16x16x32_bf16(kh, ql[ks], st[mt], 0, 0, 0);
        st[mt] = __builtin_amdgcn_mfma_f32_16x16x32_bf16(kh, qh[ks], st[mt], 0, 0, 0);
      }
    }

    // online softmax over this tile's 64 keys (stats live per q = mi, replicated over quads)
    const bool lastt = (jt == ntiles - 1);
    float tmax = -INFINITY;
    #pragma unroll
    for (int mt = 0; mt < 4; ++mt)
      #pragma unroll
      for (int r = 0; r < 4; ++r){
        float s = st[mt][r] * SCALE_F;
        if (lastt){
          int key = jt*64 + mt*16 + quad*4 + r;
          if (key > r0 + wv*16 + mi) s = -INFINITY;
        }
        st[mt][r] = s;
        tmax = fmaxf(tmax, s);
      }
    tmax = fmaxf(tmax, __shfl_xor(tmax, 16));
    tmax = fmaxf(tmax, __shfl_xor(tmax, 32));
    float mnew = fmaxf(mr, tmax);
    float alpha = __expf(mr - mnew);
    mr = mnew;
    float tsum = 0.f;
    #pragma unroll
    for (int mt = 0; mt < 4; ++mt)
      #pragma unroll
      for (int r = 0; r < 4; ++r){
        float p = __expf(st[mt][r] - mnew);
        st[mt][r] = p;
        tsum += p;
      }
    tsum += __shfl_xor(tsum, 16);
    tsum += __shfl_xor(tsum, 32);
    lr = lr*alpha + tsum;

    // write P (bf16) to per-wave pbuf: [q=mi][key]
    unsigned short* pw = Pb + wv*1152;
    #pragma unroll
    for (int mt = 0; mt < 4; ++mt){
      uint2 pk;
      pk.x = (unsigned)f2bf(st[mt][0]) | ((unsigned)f2bf(st[mt][1]) << 16);
      pk.y = (unsigned)f2bf(st[mt][2]) | ((unsigned)f2bf(st[mt][3]) << 16);
      *(uint2*)(pw + mi*ST + mt*16 + quad*4) = pk;
    }

    // rescale O by alpha (per row q = quad*4+r)
    float af[4];
    #pragma unroll
    for (int r = 0; r < 4; ++r) af[r] = __shfl(alpha, quad*4 + r);
    #pragma unroll
    for (int dn = 0; dn < 4; ++dn)
      #pragma unroll
      for (int r = 0; r < 4; ++r) O[dn][r] *= af[r];

    // PV: A = P (from pbuf), B = V^T-staged
    #pragma unroll
    for (int kt = 0; kt < 2; ++kt){
      bf16x8 pf = __builtin_bit_cast(bf16x8, *(const short8*)(pw + mi*ST + kt*32 + quad*8));
      #pragma unroll
      for (int dn = 0; dn < 4; ++dn){
        bf16x8 vf = __builtin_bit_cast(bf16x8, *(const short8*)(Vt + (dn*16 + mi)*ST + kt*32 + quad*8));
        O[dn] = __builtin_amdgcn_mfma_f32_16x16x32_bf16(pf, vf, O[dn], 0, 0, 0);
      }
    }
  }

  // write qkv = O/l to LDS overlay (rows local 0..63, stride 68 fp32)
  __syncthreads();
  float linv[4];
  #pragma unroll
  for (int r = 0; r < 4; ++r) linv[r] = 1.f / __shfl(lr, quad*4 + r);
  #pragma unroll
  for (int dn = 0; dn < 4; ++dn)
    #pragma unroll
    for (int r = 0; r < 4; ++r)
      qkvs[(wv*16 + quad*4 + r)*68 + dn*16 + mi] = O[dn][r] * linv[r];
  __syncthreads();

  // KNN memory attention + gate + bf16 round (lane = head dim)
  const float g = gate_bias[h];
  for (int rr = 0; rr < 16; ++rr){
    int trow = r0 + wv*16 + rr;
    float qd = bf2f(Qhi[(hb + trow)*64 + lane]) + bf2f(Qlo[(hb + trow)*64 + lane]);
    const int* kidx = knn_idx + ((size_t)bb*T_ + trow)*3;
    int idxs[3]; float dts[3]; float mx = -INFINITY;
    #pragma unroll
    for (int kk = 0; kk < 3; ++kk){
      int idx = kidx[kk];
      idxs[kk] = idx;
      const float* mk = mem_bank + (((size_t)bb*M_ + idx)*2 + 0)*D_ + h*HD_;
      float dkk = wsum(qd * mk[lane]) * SCALE_F;
      dts[kk] = dkk;
      mx = fmaxf(mx, dkk);
    }
    float e0 = __expf(dts[0]-mx), e1 = __expf(dts[1]-mx), e2 = __expf(dts[2]-mx);
    float inv = 1.f/(e0+e1+e2);
    const float* mv0 = mem_bank + (((size_t)bb*M_ + idxs[0])*2 + 1)*D_ + h*HD_;
    const float* mv1 = mem_bank + (((size_t)bb*M_ + idxs[1])*2 + 1)*D_ + h*HD_;
    const float* mv2 = mem_bank + (((size_t)bb*M_ + idxs[2])*2 + 1)*D_ + h*HD_;
    float ov = e0*inv*mv0[lane] + e1*inv*mv1[lane] + e2*inv*mv2[lane];
    float qkv = qkvs[(wv*16 + rr)*68 + lane];
    comb[((size_t)bb*T_ + trow)*D_ + h*HD_ + lane] = bfround(ov*g + qkv*(1.f - g));
  }
}

extern "C" void kernel_launch(void* const* d_in, const int* in_sizes, int n_in,
                              void* d_out, int out_size, void* d_ws, size_t ws_size,
                              hipStream_t stream)
{
  (void)in_sizes; (void)n_in; (void)out_size; (void)ws_size;
  const float* x    = (const float*)d_in[0];
  const float* Wq   = (const float*)d_in[1];
  const float* bq   = (const float*)d_in[2];
  const float* Wk   = (const float*)d_in[3];
  const float* bk   = (const float*)d_in[4];
  const float* Wv   = (const float*)d_in[5];
  const float* bv   = (const float*)d_in[6];
  const float* Wo   = (const float*)d_in[7];
  const float* bo   = (const float*)d_in[8];
  const float* gate = (const float*)d_in[9];
  const float* mem  = (const float*)d_in[10];
  const int*   knn  = (const int*)d_in[11];

  float* P    = (float*)d_ws;                         // 4096 x 3072 fp32
  float* comb = P + (size_t)4096 * LDP;               // 4096 x 1024 fp32
  unsigned short* Qhi = (unsigned short*)(comb + (size_t)4096*1024);
  unsigned short* Qlo = Qhi + (size_t)4096*1024;
  unsigned short* Khi = Qlo + (size_t)4096*1024;
  unsigned short* Klo = Khi + (size_t)4096*1024;
  unsigned short* Vbf = Klo + (size_t)4096*1024;

  gemm_bt<true><<<dim3(48, 32), 256, 0, stream>>>(x, D_, Wq, Wk, Wv, bq, bk, bv, P, LDP);
  norm_split<<<4096, 256, 0, stream>>>(P, Qhi, Qlo, Khi, Klo, Vbf);
  attn_knn<<<dim3(T_/64, H_, B_), 256, 0, stream>>>(Qhi, Qlo, Khi, Klo, Vbf,
                                                    mem, knn, gate, comb);
  gemm_bt<false><<<dim3(16, 32), 256, 0, stream>>>(comb, D_, Wo, Wo, Wo, bo, bo, bo,
                                                   (float*)d_out, D_);
}

// Round 3
// 620.300 us; speedup vs baseline: 4.2097x; 1.2594x over previous
//
#include <hip/hip_runtime.h>
#include <math.h>

#define B_ 2
#define T_ 2048
#define D_ 1024
#define H_ 16
#define HD_ 64
#define M_ 16384
#define SCALE_F 4096.0f
#define LDP 3072
#define ST 72            // LDS row stride (shorts) for attn tiles

using short8 = __attribute__((ext_vector_type(8))) short;
using bf16x8 = __attribute__((ext_vector_type(8))) __bf16;
using f32x4  = __attribute__((ext_vector_type(4))) float;

__device__ __forceinline__ unsigned short f2bf(float x){
  unsigned u = __builtin_bit_cast(unsigned, x);
  u += 0x7fffu + ((u >> 16) & 1u);          // RNE
  return (unsigned short)(u >> 16);
}
__device__ __forceinline__ float bf2f(unsigned short h){
  unsigned u = ((unsigned)h) << 16;
  return __builtin_bit_cast(float, u);
}
__device__ __forceinline__ float bfround(float x){ return bf2f(f2bf(x)); }

__device__ __forceinline__ float wsum(float v){
  #pragma unroll
  for (int off = 32; off; off >>= 1) v += __shfl_xor(v, off);
  return v;
}

__device__ __forceinline__ void ld_g2l16(const unsigned short* g, unsigned short* l){
  __builtin_amdgcn_global_load_lds(
      (const __attribute__((address_space(1))) void*)g,
      (__attribute__((address_space(3))) void*)l, 16, 0, 0);
}

// ---------------------------------------------------------------------------
// One-shot fp32 -> bf16 hi/lo conversion for all GEMM operands.
// grid 8192 x 256; each thread converts one float4. Block-uniform branches.
// ---------------------------------------------------------------------------
__global__ __launch_bounds__(256)
void cvt_all(const float* __restrict__ x, const float* __restrict__ Wq,
             const float* __restrict__ Wk, const float* __restrict__ Wv,
             const float* __restrict__ Wo,
             unsigned short* __restrict__ Xhi, unsigned short* __restrict__ Xlo,
             unsigned short* __restrict__ Whi, unsigned short* __restrict__ Wlo,
             unsigned short* __restrict__ Wohi)
{
  const int i = blockIdx.x*256 + threadIdx.x;
  const float* src; unsigned short* hi; unsigned short* lo = nullptr; int rel;
  if      (i < 1048576){ src = x;  hi = Xhi;            lo = Xlo;            rel = i; }
  else if (i < 1310720){ src = Wq; hi = Whi;            lo = Wlo;            rel = i - 1048576; }
  else if (i < 1572864){ src = Wk; hi = Whi + 1048576;  lo = Wlo + 1048576;  rel = i - 1310720; }
  else if (i < 1835008){ src = Wv; hi = Whi + 2097152;                       rel = i - 1572864; }
  else                 { src = Wo; hi = Wohi;                                rel = i - 1835008; }
  float4 v = *(const float4*)(src + (size_t)rel*4);
  unsigned short h0=f2bf(v.x), h1=f2bf(v.y), h2=f2bf(v.z), h3=f2bf(v.w);
  uint2 hh; hh.x = (unsigned)h0 | ((unsigned)h1 << 16);
            hh.y = (unsigned)h2 | ((unsigned)h3 << 16);
  *(uint2*)(hi + (size_t)rel*4) = hh;
  if (lo){
    uint2 ll;
    ll.x = (unsigned)f2bf(v.x-bf2f(h0)) | ((unsigned)f2bf(v.y-bf2f(h1)) << 16);
    ll.y = (unsigned)f2bf(v.z-bf2f(h2)) | ((unsigned)f2bf(v.w-bf2f(h3)) << 16);
    *(uint2*)(lo + (size_t)rel*4) = ll;
  }
}

// ---------------------------------------------------------------------------
// m97-structure GEMM: C[m, n0+n] = sum_k A[m,k]*B[n,k] + bias[n]
// A,B pre-converted bf16 (hi/lo), K=1024. Tile 128x128, BK=32, 256 thr =
// 2x2 waves, each wave 4x4 16x16x32 accumulators. All staging via
// global_load_lds width=16 (unpadded LDS, wave-uniform-base rule).
// COMP: hi/lo compensation (3x MFMA) for n-segments 0,1 (q,k).
// ---------------------------------------------------------------------------
template<bool COMP>
__global__ __launch_bounds__(256)
void gemm_lds(const unsigned short* __restrict__ Ahi_g, const unsigned short* __restrict__ Alo_g,
              const unsigned short* __restrict__ Bhi_g, const unsigned short* __restrict__ Blo_g,
              const float* __restrict__ bias0, const float* __restrict__ bias1,
              const float* __restrict__ bias2,
              float* __restrict__ C, int ldc)
{
  __shared__ __align__(16) unsigned short Ah[128*32];
  __shared__ __align__(16) unsigned short Bh[128*32];
  __shared__ __align__(16) unsigned short Al[COMP ? 128*32 : 8];
  __shared__ __align__(16) unsigned short Bl[COMP ? 128*32 : 8];

  const int tid = threadIdx.x, lane = tid & 63, wv = tid >> 6;
  const int wm = wv >> 1, wn = wv & 1;
  const int mi = lane & 15, quad = lane >> 4;
  const int n0 = blockIdx.x * 128;
  const int m0 = blockIdx.y * 128;
  const int seg = n0 >> 10;
  const float* bias = (seg == 0) ? bias0 : (seg == 1) ? bias1 : bias2;
  const int nw = n0 & 1023;
  const bool comp = COMP && (seg < 2);

  f32x4 acc[4][4];
  #pragma unroll
  for (int a = 0; a < 4; ++a)
    #pragma unroll
    for (int b = 0; b < 4; ++b)
      acc[a][b] = (f32x4){0.f, 0.f, 0.f, 0.f};

  for (int k0 = 0; k0 < 1024; k0 += 32){
    __syncthreads();
    #pragma unroll
    for (int t = 0; t < 2; ++t){
      int j = wv*128 + t*64 + lane;           // 16B chunk id; lds = base + lane*16
      int row = j >> 2, c16 = j & 3;
      size_t ga = (size_t)(m0 + row)*1024 + k0 + c16*8;
      size_t gb = (size_t)(n0 + row)*1024 + k0 + c16*8;
      ld_g2l16(Ahi_g + ga, Ah + j*8);
      ld_g2l16(Bhi_g + gb, Bh + j*8);
      if (comp){
        ld_g2l16(Alo_g + ga, Al + j*8);
        ld_g2l16(Blo_g + gb, Bl + j*8);
      }
    }
    __syncthreads();

    bf16x8 ah[4], al[4];
    #pragma unroll
    for (int a = 0; a < 4; ++a){
      int r = wm*64 + a*16 + mi;
      ah[a] = __builtin_bit_cast(bf16x8, *(const short8*)(Ah + r*32 + quad*8));
      if (comp)
        al[a] = __builtin_bit_cast(bf16x8, *(const short8*)(Al + r*32 + quad*8));
    }
    #pragma unroll
    for (int b = 0; b < 4; ++b){
      int r = wn*64 + b*16 + mi;
      bf16x8 bh = __builtin_bit_cast(bf16x8, *(const short8*)(Bh + r*32 + quad*8));
      if (comp){
        bf16x8 bl = __builtin_bit_cast(bf16x8, *(const short8*)(Bl + r*32 + quad*8));
        #pragma unroll
        for (int a = 0; a < 4; ++a){
          acc[a][b] = __builtin_amdgcn_mfma_f32_16x16x32_bf16(al[a], bh, acc[a][b], 0, 0, 0);
          acc[a][b] = __builtin_amdgcn_mfma_f32_16x16x32_bf16(ah[a], bl, acc[a][b], 0, 0, 0);
          acc[a][b] = __builtin_amdgcn_mfma_f32_16x16x32_bf16(ah[a], bh, acc[a][b], 0, 0, 0);
        }
      } else {
        #pragma unroll
        for (int a = 0; a < 4; ++a)
          acc[a][b] = __builtin_amdgcn_mfma_f32_16x16x32_bf16(ah[a], bh, acc[a][b], 0, 0, 0);
      }
    }
  }
  // C/D layout: col = lane&15 (n), row = quad*4 + reg (m)  [m89/m91-verified]
  #pragma unroll
  for (int a = 0; a < 4; ++a)
    #pragma unroll
    for (int b = 0; b < 4; ++b)
      #pragma unroll
      for (int r = 0; r < 4; ++r){
        int row  = m0 + wm*64 + a*16 + quad*4 + r;
        int coll = wn*64 + b*16 + mi;
        C[(size_t)row*ldc + n0 + coll] = acc[a][b][r] + bias[nw + coll];
      }
}

// ---------------------------------------------------------------------------
// Normalize q,k rows of P; emit head-major bf16: Qhi/Qlo/Khi/Klo/Vbf
// ---------------------------------------------------------------------------
__global__ __launch_bounds__(256)
void norm_split(const float* __restrict__ P,
                unsigned short* __restrict__ Qhi, unsigned short* __restrict__ Qlo,
                unsigned short* __restrict__ Khi, unsigned short* __restrict__ Klo,
                unsigned short* __restrict__ Vbf)
{
  const int row = blockIdx.x, tid = threadIdx.x;
  const int bb = row >> 11, t = row & 2047;
  const int lane = tid & 63, wv = tid >> 6;
  const size_t base = (size_t)row * LDP;
  float4 q4 = *(const float4*)(P + base + tid*4);
  float4 k4 = *(const float4*)(P + base + 1024 + tid*4);
  float4 v4 = *(const float4*)(P + base + 2048 + tid*4);
  float sq = wsum(q4.x*q4.x + q4.y*q4.y + q4.z*q4.z + q4.w*q4.w);
  float sk = wsum(k4.x*k4.x + k4.y*k4.y + k4.z*k4.z + k4.w*k4.w);
  __shared__ float rq[4], rk[4];
  if (lane == 0){ rq[wv] = sq; rk[wv] = sk; }
  __syncthreads();
  float cq = 1.f / fmaxf(sqrtf(rq[0]+rq[1]+rq[2]+rq[3]), 1e-12f);
  float ck = 1.f / fmaxf(sqrtf(rk[0]+rk[1]+rk[2]+rk[3]), 1e-12f);
  float qf[4] = {q4.x*cq, q4.y*cq, q4.z*cq, q4.w*cq};
  float kf[4] = {k4.x*ck, k4.y*ck, k4.z*ck, k4.w*ck};

  const int h = tid >> 4, d0 = (tid & 15)*4;
  const size_t ob = ((size_t)(bb*H_ + h)*T_ + t)*64 + d0;

  uint2 qh, ql, kh, kl, vv;
  unsigned short t0,t1,t2,t3;
  t0=f2bf(qf[0]); t1=f2bf(qf[1]); t2=f2bf(qf[2]); t3=f2bf(qf[3]);
  qh.x = t0 | ((unsigned)t1<<16); qh.y = t2 | ((unsigned)t3<<16);
  ql.x = f2bf(qf[0]-bf2f(t0)) | ((unsigned)f2bf(qf[1]-bf2f(t1))<<16);
  ql.y = f2bf(qf[2]-bf2f(t2)) | ((unsigned)f2bf(qf[3]-bf2f(t3))<<16);
  t0=f2bf(kf[0]); t1=f2bf(kf[1]); t2=f2bf(kf[2]); t3=f2bf(kf[3]);
  kh.x = t0 | ((unsigned)t1<<16); kh.y = t2 | ((unsigned)t3<<16);
  kl.x = f2bf(kf[0]-bf2f(t0)) | ((unsigned)f2bf(kf[1]-bf2f(t1))<<16);
  kl.y = f2bf(kf[2]-bf2f(t2)) | ((unsigned)f2bf(kf[3]-bf2f(t3))<<16);
  vv.x = f2bf(v4.x) | ((unsigned)f2bf(v4.y)<<16);
  vv.y = f2bf(v4.z) | ((unsigned)f2bf(v4.w)<<16);
  *(uint2*)(Qhi + ob) = qh;  *(uint2*)(Qlo + ob) = ql;
  *(uint2*)(Khi + ob) = kh;  *(uint2*)(Klo + ob) = kl;
  *(uint2*)(Vbf + ob) = vv;
}

// ---------------------------------------------------------------------------
// MFMA flash attention + KNN + gate. Grid (T/64, H, B), 4 waves x 16 q-rows.
// comb written as bf16 (exact under ref's bf16 round).
// ---------------------------------------------------------------------------
__global__ __launch_bounds__(256)
void attn_knn(const unsigned short* __restrict__ Qhi, const unsigned short* __restrict__ Qlo,
              const unsigned short* __restrict__ Khi_g, const unsigned short* __restrict__ Klo_g,
              const unsigned short* __restrict__ Vbf,
              const float* __restrict__ mem_bank, const int* __restrict__ knn_idx,
              const float* __restrict__ gate_bias, unsigned short* __restrict__ comb)
{
  __shared__ char smpool[36864];
  unsigned short* Kh = (unsigned short*)smpool;            // 64*72
  unsigned short* Kl = (unsigned short*)(smpool + 9216);
  unsigned short* Vt = (unsigned short*)(smpool + 18432);  // [d][key] packed pairs
  unsigned short* Pb = (unsigned short*)(smpool + 27648);  // 4 waves * 16*72
  float* qkvs = (float*)smpool;                            // overlay 64 x 68 fp32

  const int bb = blockIdx.z, h = blockIdx.y;
  const int r0 = blockIdx.x * 64;
  const int tid = threadIdx.x, lane = tid & 63, wv = tid >> 6;
  const int mi = lane & 15, quad = lane >> 4;
  const size_t hb = (size_t)(bb*H_ + h)*T_;

  const int qrow = r0 + wv*16 + mi;
  bf16x8 qh[2], ql[2];
  #pragma unroll
  for (int ks = 0; ks < 2; ++ks){
    qh[ks] = __builtin_bit_cast(bf16x8, *(const uint4*)(Qhi + (hb + qrow)*64 + ks*32 + quad*8));
    ql[ks] = __builtin_bit_cast(bf16x8, *(const uint4*)(Qlo + (hb + qrow)*64 + ks*32 + quad*8));
  }

  f32x4 O[4];
  #pragma unroll
  for (int dn = 0; dn < 4; ++dn) O[dn] = (f32x4){0.f,0.f,0.f,0.f};
  float mr = -INFINITY, lr = 0.f;

  const int ntiles = blockIdx.x + 1;
  for (int jt = 0; jt < ntiles; ++jt){
    __syncthreads();
    #pragma unroll
    for (int i = 0; i < 4; ++i){
      int idx = tid + i*256;
      int row = idx >> 4, c4 = idx & 15;
      size_t g = (hb + jt*64 + row)*64 + c4*4;
      *(uint2*)(Kh + row*ST + c4*4) = *(const uint2*)(Khi_g + g);
      *(uint2*)(Kl + row*ST + c4*4) = *(const uint2*)(Klo_g + g);
    }
    #pragma unroll
    for (int i = 0; i < 2; ++i){
      int idx = tid + i*256;
      int rp = idx & 31, d4 = idx >> 5;
      size_t g = (hb + jt*64 + 2*rp)*64 + d4*4;
      ushort4 a = *(const ushort4*)(Vbf + g);
      ushort4 b = *(const ushort4*)(Vbf + g + 64);
      unsigned* vt = (unsigned*)Vt;
      vt[(d4*4+0)*36 + rp] = (unsigned)a.x | ((unsigned)b.x << 16);
      vt[(d4*4+1)*36 + rp] = (unsigned)a.y | ((unsigned)b.y << 16);
      vt[(d4*4+2)*36 + rp] = (unsigned)a.z | ((unsigned)b.z << 16);
      vt[(d4*4+3)*36 + rp] = (unsigned)a.w | ((unsigned)b.w << 16);
    }
    __syncthreads();

    f32x4 st[4];
    #pragma unroll
    for (int mt = 0; mt < 4; ++mt) st[mt] = (f32x4){0.f,0.f,0.f,0.f};
    #pragma unroll
    for (int mt = 0; mt < 4; ++mt){
      int krow = mt*16 + mi;
      #pragma unroll
      for (int ks = 0; ks < 2; ++ks){
        bf16x8 kh = __builtin_bit_cast(bf16x8, *(const short8*)(Kh + krow*ST + ks*32 + quad*8));
        bf16x8 kl = __builtin_bit_cast(bf16x8, *(const short8*)(Kl + krow*ST + ks*32 + quad*8));
        st[mt] = __builtin_amdgcn_mfma_f32_16x16x32_bf16(kl, qh[ks], st[mt], 0, 0, 0);
        st[mt] = __builtin_amdgcn_mfma_f32_16x16x32_bf16(kh, ql[ks], st[mt], 0, 0, 0);
        st[mt] = __builtin_amdgcn_mfma_f32_16x16x32_bf16(kh, qh[ks], st[mt], 0, 0, 0);
      }
    }

    const bool lastt = (jt == ntiles - 1);
    float tmax = -INFINITY;
    #pragma unroll
    for (int mt = 0; mt < 4; ++mt)
      #pragma unroll
      for (int r = 0; r < 4; ++r){
        float s = st[mt][r] * SCALE_F;
        if (lastt){
          int key = jt*64 + mt*16 + quad*4 + r;
          if (key > r0 + wv*16 + mi) s = -INFINITY;
        }
        st[mt][r] = s;
        tmax = fmaxf(tmax, s);
      }
    tmax = fmaxf(tmax, __shfl_xor(tmax, 16));
    tmax = fmaxf(tmax, __shfl_xor(tmax, 32));
    float mnew = fmaxf(mr, tmax);
    float alpha = __expf(mr - mnew);
    mr = mnew;
    float tsum = 0.f;
    #pragma unroll
    for (int mt = 0; mt < 4; ++mt)
      #pragma unroll
      for (int r = 0; r < 4; ++r){
        float p = __expf(st[mt][r] - mnew);
        st[mt][r] = p;
        tsum += p;
      }
    tsum += __shfl_xor(tsum, 16);
    tsum += __shfl_xor(tsum, 32);
    lr = lr*alpha + tsum;

    unsigned short* pw = Pb + wv*1152;
    #pragma unroll
    for (int mt = 0; mt < 4; ++mt){
      uint2 pk;
      pk.x = (unsigned)f2bf(st[mt][0]) | ((unsigned)f2bf(st[mt][1]) << 16);
      pk.y = (unsigned)f2bf(st[mt][2]) | ((unsigned)f2bf(st[mt][3]) << 16);
      *(uint2*)(pw + mi*ST + mt*16 + quad*4) = pk;
    }

    float af[4];
    #pragma unroll
    for (int r = 0; r < 4; ++r) af[r] = __shfl(alpha, quad*4 + r);
    #pragma unroll
    for (int dn = 0; dn < 4; ++dn)
      #pragma unroll
      for (int r = 0; r < 4; ++r) O[dn][r] *= af[r];

    #pragma unroll
    for (int kt = 0; kt < 2; ++kt){
      bf16x8 pf = __builtin_bit_cast(bf16x8, *(const short8*)(pw + mi*ST + kt*32 + quad*8));
      #pragma unroll
      for (int dn = 0; dn < 4; ++dn){
        bf16x8 vf = __builtin_bit_cast(bf16x8, *(const short8*)(Vt + (dn*16 + mi)*ST + kt*32 + quad*8));
        O[dn] = __builtin_amdgcn_mfma_f32_16x16x32_bf16(pf, vf, O[dn], 0, 0, 0);
      }
    }
  }

  __syncthreads();
  float linv[4];
  #pragma unroll
  for (int r = 0; r < 4; ++r) linv[r] = 1.f / __shfl(lr, quad*4 + r);
  #pragma unroll
  for (int dn = 0; dn < 4; ++dn)
    #pragma unroll
    for (int r = 0; r < 4; ++r)
      qkvs[(wv*16 + quad*4 + r)*68 + dn*16 + mi] = O[dn][r] * linv[r];
  __syncthreads();

  const float g = gate_bias[h];
  for (int rr = 0; rr < 16; ++rr){
    int trow = r0 + wv*16 + rr;
    float qd = bf2f(Qhi[(hb + trow)*64 + lane]) + bf2f(Qlo[(hb + trow)*64 + lane]);
    const int* kidx = knn_idx + ((size_t)bb*T_ + trow)*3;
    int idxs[3]; float dts[3]; float mx = -INFINITY;
    #pragma unroll
    for (int kk = 0; kk < 3; ++kk){
      int idx = kidx[kk];
      idxs[kk] = idx;
      const float* mk = mem_bank + (((size_t)bb*M_ + idx)*2 + 0)*D_ + h*HD_;
      float dkk = wsum(qd * mk[lane]) * SCALE_F;
      dts[kk] = dkk;
      mx = fmaxf(mx, dkk);
    }
    float e0 = __expf(dts[0]-mx), e1 = __expf(dts[1]-mx), e2 = __expf(dts[2]-mx);
    float inv = 1.f/(e0+e1+e2);
    const float* mv0 = mem_bank + (((size_t)bb*M_ + idxs[0])*2 + 1)*D_ + h*HD_;
    const float* mv1 = mem_bank + (((size_t)bb*M_ + idxs[1])*2 + 1)*D_ + h*HD_;
    const float* mv2 = mem_bank + (((size_t)bb*M_ + idxs[2])*2 + 1)*D_ + h*HD_;
    float ov = e0*inv*mv0[lane] + e1*inv*mv1[lane] + e2*inv*mv2[lane];
    float qkv = qkvs[(wv*16 + rr)*68 + lane];
    comb[((size_t)bb*T_ + trow)*D_ + h*HD_ + lane] = f2bf(ov*g + qkv*(1.f - g));
  }
}

extern "C" void kernel_launch(void* const* d_in, const int* in_sizes, int n_in,
                              void* d_out, int out_size, void* d_ws, size_t ws_size,
                              hipStream_t stream)
{
  (void)in_sizes; (void)n_in; (void)out_size; (void)ws_size;
  const float* x    = (const float*)d_in[0];
  const float* Wq   = (const float*)d_in[1];
  const float* bq   = (const float*)d_in[2];
  const float* Wk   = (const float*)d_in[3];
  const float* bk   = (const float*)d_in[4];
  const float* Wv   = (const float*)d_in[5];
  const float* bv   = (const float*)d_in[6];
  const float* Wo   = (const float*)d_in[7];
  const float* bo   = (const float*)d_in[8];
  const float* gate = (const float*)d_in[9];
  const float* mem  = (const float*)d_in[10];
  const int*   knn  = (const int*)d_in[11];

  char* ws = (char*)d_ws;
  float*          P    = (float*)ws;                               // 48 MB
  unsigned short* comb = (unsigned short*)ws;                      // 8 MB, aliases P (P dead after norm)
  unsigned short* Qhi  = (unsigned short*)(ws +  50331648);
  unsigned short* Qlo  = (unsigned short*)(ws +  58720256);
  unsigned short* Khi  = (unsigned short*)(ws +  67108864);
  unsigned short* Klo  = (unsigned short*)(ws +  75497472);
  unsigned short* Vbf  = (unsigned short*)(ws +  83886080);
  unsigned short* Xhi  = (unsigned short*)(ws +  92274688);
  unsigned short* Xlo  = (unsigned short*)(ws + 100663296);
  unsigned short* Whi  = (unsigned short*)(ws + 109051904);        // 3072x1024
  unsigned short* Wlo  = (unsigned short*)(ws + 115343360);        // 2048x1024 (q,k only)
  unsigned short* Wohi = (unsigned short*)(ws + 119537664);        // 1024x1024

  cvt_all<<<8192, 256, 0, stream>>>(x, Wq, Wk, Wv, Wo, Xhi, Xlo, Whi, Wlo, Wohi);
  gemm_lds<true><<<dim3(24, 32), 256, 0, stream>>>(Xhi, Xlo, Whi, Wlo, bq, bk, bv, P, LDP);
  norm_split<<<4096, 256, 0, stream>>>(P, Qhi, Qlo, Khi, Klo, Vbf);
  attn_knn<<<dim3(T_/64, H_, B_), 256, 0, stream>>>(Qhi, Qlo, Khi, Klo, Vbf,
                                                    mem, knn, gate, comb);
  gemm_lds<false><<<dim3(8, 32), 256, 0, stream>>>(comb, nullptr, Wohi, nullptr,
                                                   bo, bo, bo, (float*)d_out, D_);
}